// Round 12
// baseline (504.674 us; speedup 1.0000x reference)
//
#include <hip/hip_runtime.h>
#include <stdint.h>

typedef _Float16 f16;
typedef __attribute__((ext_vector_type(8))) _Float16 half8;
typedef __attribute__((ext_vector_type(2))) __fp16 fp16x2;
typedef __attribute__((ext_vector_type(8))) short short8;
typedef __attribute__((ext_vector_type(4))) float f32x4;

#define NPOS 4096
#define CCH  256
#define OQK  64
#define BATCH 2
#define NSPLIT 4
#define KEYS_PER_SPLIT 1024
#define NT (KEYS_PER_SPLIT / 64)

typedef __attribute__((address_space(3))) uint32_t lds_u32;
typedef __attribute__((address_space(1))) const uint32_t glb_u32;

__device__ __forceinline__ float bf2f(short u) {
    union { uint32_t i; float f; } c;
    c.i = ((uint32_t)(uint16_t)u) << 16;
    return c.f;
}
__device__ __forceinline__ short f2bf(float f) {
    union { float f; uint32_t i; } c; c.f = f;
    uint32_t lsb = (c.i >> 16) & 1u;
    c.i += 0x7FFFu + lsb;
    return (short)(c.i >> 16);
}

// Deterministic dtype sniff: mask values are exactly {0.0,1.0}.
__device__ __forceinline__ bool detect_bf16(const uint32_t* mw) {
    int hits = 0;
    #pragma unroll
    for (int i = 0; i < 64; ++i) hits += ((mw[i] & 0xFFFFu) == 0x3F80u) ? 1 : 0;
    return hits != 0;
}

__device__ __forceinline__ void load8(const void* base, size_t e0, bool bf, float* v) {
    if (bf) {
        short8 s = *(const short8*)((const short*)base + e0);
        #pragma unroll
        for (int j = 0; j < 8; ++j) v[j] = bf2f(s[j]);
    } else {
        const float* fp = (const float*)base + e0;
        float4 a = *(const float4*)fp;
        float4 b = *(const float4*)(fp + 4);
        v[0] = a.x; v[1] = a.y; v[2] = a.z; v[3] = a.w;
        v[4] = b.x; v[5] = b.y; v[6] = b.z; v[7] = b.w;
    }
}
__device__ __forceinline__ float load1(const void* base, int i, bool bf) {
    return bf ? bf2f(((const short*)base)[i]) : ((const float*)base)[i];
}

__device__ __forceinline__ int pkrtz(float a, float b) {
    union { fp16x2 h; int i; } u;
    u.h = __builtin_amdgcn_cvt_pkrtz(a, b);
    return u.i;
}

// ---------------------------------------------------------------------------
// Canonicalize small inputs. grid = 85 blocks x 256.
// ---------------------------------------------------------------------------
__global__ __launch_bounds__(256) void convert_inputs(
    const uint32_t* __restrict__ mask_raw,
    const void* __restrict__ w1q, const void* __restrict__ w1k, const void* __restrict__ w1v_,
    const void* __restrict__ b1q, const void* __restrict__ b1k, const void* __restrict__ b1v_,
    const void* __restrict__ g1,
    const void* __restrict__ w2q, const void* __restrict__ w2k, const void* __restrict__ w2v_,
    const void* __restrict__ b2q, const void* __restrict__ b2k, const void* __restrict__ b2v_,
    const void* __restrict__ g2,
    float* __restrict__ maskf,
    f16* __restrict__ w1qk, f16* __restrict__ w1vm, f16* __restrict__ b1,
    f16* __restrict__ w2qk, f16* __restrict__ w2vm, f16* __restrict__ b2,
    float* __restrict__ gam)
{
    const bool bf = detect_bf16(mask_raw);
    const int blk = blockIdx.x, tid = threadIdx.x;
    float v[8];
    if (blk < 4) {                          // mask: 8192
        const size_t e0 = ((size_t)blk * 256 + tid) * 8;
        load8(mask_raw, e0, bf, v);
        float4 f0 = {v[0], v[1], v[2], v[3]}, f1 = {v[4], v[5], v[6], v[7]};
        *(float4*)(maskf + e0) = f0;
        *(float4*)(maskf + e0 + 4) = f1;
    } else if (blk < 12) {                  // w1qk: 16384
        const size_t g = ((size_t)(blk - 4) * 256 + tid) * 8;
        const int o = (int)(g >> 8), cc = (int)(g & 255);
        const void* src = (o < 32) ? w1q : w1k;
        const size_t se = (size_t)((o < 32) ? o : o - 32) * 256 + cc;
        load8(src, se, bf, v);
        half8 h;
        #pragma unroll
        for (int j = 0; j < 8; ++j) h[j] = (f16)v[j];
        *(half8*)(w1qk + g) = h;
    } else if (blk < 44) {                  // w1v: 65536
        const size_t g = ((size_t)(blk - 12) * 256 + tid) * 8;
        load8(w1v_, g, bf, v);
        half8 h;
        #pragma unroll
        for (int j = 0; j < 8; ++j) h[j] = (f16)v[j];
        *(half8*)(w1vm + g) = h;
    } else if (blk < 52) {                  // w2qk
        const size_t g = ((size_t)(blk - 44) * 256 + tid) * 8;
        const int o = (int)(g >> 8), cc = (int)(g & 255);
        const void* src = (o < 32) ? w2q : w2k;
        const size_t se = (size_t)((o < 32) ? o : o - 32) * 256 + cc;
        load8(src, se, bf, v);
        half8 h;
        #pragma unroll
        for (int j = 0; j < 8; ++j) h[j] = (f16)v[j];
        *(half8*)(w2qk + g) = h;
    } else if (blk < 84) {                  // w2v
        const size_t g = ((size_t)(blk - 52) * 256 + tid) * 8;
        load8(w2v_, g, bf, v);
        half8 h;
        #pragma unroll
        for (int j = 0; j < 8; ++j) h[j] = (f16)v[j];
        *(half8*)(w2vm + g) = h;
    } else {                                // biases + gammas
        for (int i = tid; i < 320; i += 256) {
            const void* s1 = (i < 32) ? b1q : (i < 64) ? b1k : b1v_;
            const void* s2 = (i < 32) ? b2q : (i < 64) ? b2k : b2v_;
            const int ii = (i < 32) ? i : (i < 64) ? i - 32 : i - 64;
            b1[i] = (f16)load1(s1, ii, bf);
            b2[i] = (f16)load1(s2, ii, bf);
        }
        if (tid == 0) {
            gam[0] = load1(g1, 0, bf);
            gam[1] = load1(g2, 0, bf);
        }
    }
}

// ---------------------------------------------------------------------------
// Fused 1x1 conv: q,k packed (B,N,64); v (B,C,N); f16 out.
// ---------------------------------------------------------------------------
__global__ __launch_bounds__(256) void conv_qkv(
    const void* __restrict__ xin, int is_raw,
    const uint32_t* __restrict__ mask_raw,
    const f16* __restrict__ wqk,
    const f16* __restrict__ wvm,
    const f16* __restrict__ bias,
    const float* __restrict__ maskf, int use_mask,
    f16* __restrict__ qkout,
    f16* __restrict__ vout)
{
    const bool bf = is_raw ? detect_bf16(mask_raw) : false;
    const int b    = blockIdx.y;
    const int n0   = blockIdx.x * 32;
    const int tid  = threadIdx.x;
    const int lane = tid & 63;
    const int w    = tid >> 6;
    const int lo   = lane & 15;
    const int hi   = lane >> 4;

    __shared__ f16 xt[32 * 256];   // [n][c], 16 KB

    {
        const int nc = tid & 3;
        const int cg = tid >> 2;
        #pragma unroll
        for (int it = 0; it < 4; ++it) {
            const int c = cg + 64 * it;
            const size_t off = ((size_t)b * CCH + c) * NPOS + n0 + nc * 8;
            float v8[8];
            load8(xin, off, bf, v8);
            #pragma unroll
            for (int j = 0; j < 8; ++j) {
                const int n = nc * 8 + j;
                int byte = n * 512 + c * 2;
                byte ^= ((n & 7) << 4);
                *(f16*)((char*)xt + byte) = (f16)v8[j];
            }
        }
    }
    __syncthreads();

    const f32x4 z = {0.f, 0.f, 0.f, 0.f};
    f32x4 acc_qk[2];
    f32x4 acc_v[4][2];
    #pragma unroll
    for (int i = 0; i < 2; ++i) {
        acc_qk[i] = z;
        #pragma unroll
        for (int j = 0; j < 4; ++j) acc_v[j][i] = z;
    }

    #pragma unroll 1
    for (int ks = 0; ks < 8; ++ks) {
        const int ce = ks * 32 + 8 * hi;
        half8 xfr[2];
        #pragma unroll
        for (int nt = 0; nt < 2; ++nt) {
            const int n = nt * 16 + lo;
            int byte = n * 512 + ce * 2;
            byte ^= ((n & 7) << 4);
            xfr[nt] = *(const half8*)((const char*)xt + byte);
        }
        {
            half8 wf = *(const half8*)(wqk + (size_t)(w * 16 + lo) * 256 + ce);
            #pragma unroll
            for (int nt = 0; nt < 2; ++nt)
                acc_qk[nt] = __builtin_amdgcn_mfma_f32_16x16x32_f16(xfr[nt], wf, acc_qk[nt], 0, 0, 0);
        }
        #pragma unroll
        for (int ot = 0; ot < 4; ++ot) {
            half8 wf = *(const half8*)(wvm + (size_t)(w * 64 + ot * 16 + lo) * 256 + ce);
            #pragma unroll
            for (int nt = 0; nt < 2; ++nt)
                acc_v[ot][nt] = __builtin_amdgcn_mfma_f32_16x16x32_f16(wf, xfr[nt], acc_v[ot][nt], 0, 0, 0);
        }
    }

    {
        const int o = w * 16 + lo;
        const float bb = (float)bias[o];
        #pragma unroll
        for (int nt = 0; nt < 2; ++nt) {
            #pragma unroll
            for (int r = 0; r < 4; ++r) {
                const int n = n0 + nt * 16 + 4 * hi + r;
                float mult = 1.f;
                if (use_mask) {
                    const float mv = maskf[b * NPOS + n];
                    mult = (o < 32) ? mv : (1.f - mv);
                }
                qkout[((size_t)b * NPOS + n) * OQK + o] = (f16)(mult * acc_qk[nt][r] + bb);
            }
        }
    }
    {
        float mv_n[2];
        #pragma unroll
        for (int nt = 0; nt < 2; ++nt)
            mv_n[nt] = use_mask ? (1.f - maskf[b * NPOS + n0 + nt * 16 + lo]) : 1.f;
        #pragma unroll
        for (int ot = 0; ot < 4; ++ot) {
            #pragma unroll
            for (int r = 0; r < 4; ++r) {
                const int oc = w * 64 + ot * 16 + 4 * hi + r;
                const float bb = (float)bias[64 + oc];
                #pragma unroll
                for (int nt = 0; nt < 2; ++nt) {
                    const int n = n0 + nt * 16 + lo;
                    vout[((size_t)b * CCH + oc) * NPOS + n] = (f16)(mv_n[nt] * acc_v[ot][nt][r] + bb);
                }
            }
        }
    }
}

// ---------------------------------------------------------------------------
// Split-KV flash attention v7 as TEMPLATE for phase ablation (rule #17: all
// skipped phases keep LDS side-effect producers/consumers; barriers + waits
// kept as skeleton in every mode).
// MODE bit 1: skip K/V staging. bit 2: skip owner (QK+softmax+P write).
// bit 4: skip PV (rescale+frag reads+MFMA).
// q0 masked by 63 so diagnostic launches can use 4x grid.
// ---------------------------------------------------------------------------
template <int MODE>
__global__ __launch_bounds__(512, 4) void attn_split_t(
    const f16* __restrict__ qk,
    const f16* __restrict__ vbuf,
    f16* __restrict__ po,
    float2* __restrict__ pml)
{
    const int b     = blockIdx.z;
    const int split = blockIdx.y;
    const int tid   = threadIdx.x;
    const int lane  = tid & 63;
    const int w     = tid >> 6;
    const int lo    = lane & 15;
    const int hi    = lane >> 4;
    const int q0    = (blockIdx.x & 63) * 64;
    const int qown  = (w & 3) * 16;
    const int cbase = w * 32;

    __shared__ f16 kv[CCH * 64];
    __shared__ f16 kbuf[2][64 * 64];
    __shared__ f16 plds[64 * 64];
    __shared__ float sc_lds[64];
    __shared__ float l_lds[64];
    __shared__ int   flag_lds[4];

    const int trow = tid >> 3;
    const int tch  = tid & 7;

    if (tid < 4) flag_lds[tid] = 0;

    half8 qfrag;
    if (w < 4)
        qfrag = *(const half8*)(qk + ((size_t)b * NPOS + q0 + qown + lo) * OQK + 8 * hi);

    const f32x4 z = {0.f, 0.f, 0.f, 0.f};
    f32x4 acc[2][4];
    #pragma unroll
    for (int i = 0; i < 2; ++i)
        #pragma unroll
        for (int j = 0; j < 4; ++j) acc[i][j] = z;
    float m_run = -3.0e38f, l_run = 0.f;

    const f16* vsrc = vbuf + (size_t)b * CCH * NPOS;
    const f16* ksrc = qk + (size_t)b * NPOS * OQK;

    #define STAGE_V(kt)                                                        \
    {                                                                          \
        const int j0s = split * KEYS_PER_SPLIT + (kt) * 64;                    \
        _Pragma("unroll")                                                      \
        for (int i = 0; i < 4; ++i) {                                          \
            const int c = i * 64 + trow;                                       \
            const f16* g = vsrc + (size_t)c * NPOS + j0s + ((tch ^ (c & 7)) * 8); \
            char* d = (char*)kv + i * 8192 + w * 1024;                         \
            __builtin_amdgcn_global_load_lds((glb_u32*)g, (lds_u32*)d, 16, 0, 0); \
        }                                                                      \
    }
    #define STAGE_K(kt)                                                        \
    {                                                                          \
        const int j0s = split * KEYS_PER_SPLIT + (kt) * 64;                    \
        char* kb = (char*)kbuf + ((kt) & 1) * 8192;                            \
        const f16* g = ksrc + (size_t)(j0s + trow) * OQK + ((tch ^ (trow & 7)) * 8); \
        __builtin_amdgcn_global_load_lds((glb_u32*)g, (lds_u32*)(kb + w * 1024), 16, 0, 0); \
    }

    if constexpr (!(MODE & 1)) {
        STAGE_V(0)
        STAGE_K(0)
        STAGE_K(1)
    }
    asm volatile("s_waitcnt vmcnt(1)" ::: "memory");
    __builtin_amdgcn_s_barrier();
    asm volatile("" ::: "memory");

    #pragma unroll 1
    for (int kt = 0; kt < NT; ++kt) {
        // ---- owner phase
        if constexpr (!(MODE & 2)) {
            if (w < 4) {
                const char* kb = (const char*)kbuf + (kt & 1) * 8192;
                f32x4 s[4];
                __builtin_amdgcn_s_setprio(1);
                #pragma unroll
                for (int jt = 0; jt < 4; ++jt) {
                    const int krow = jt * 16 + lo;
                    const half8 kfrag = *(const half8*)(kb + krow * 128
                                                        + ((64 + hi * 16) ^ ((krow & 7) << 4)));
                    s[jt] = __builtin_amdgcn_mfma_f32_16x16x32_f16(kfrag, qfrag, z, 0, 0, 0);
                }
                __builtin_amdgcn_s_setprio(0);
                float pm = s[0][0];
                #pragma unroll
                for (int jt = 0; jt < 4; ++jt)
                    #pragma unroll
                    for (int r = 0; r < 4; ++r) pm = fmaxf(pm, s[jt][r]);
                pm = fmaxf(pm, __shfl_xor(pm, 16, 64));
                pm = fmaxf(pm, __shfl_xor(pm, 32, 64));
                const bool g = __any(pm - m_run > 8.f);
                float scv = 1.f;
                if (g) {
                    const float mnew = fmaxf(m_run, pm);
                    scv = __expf(m_run - mnew);
                    m_run = mnew;
                    l_run *= scv;
                }
                float rs = 0.f;
                #pragma unroll
                for (int jt = 0; jt < 4; ++jt) {
                    #pragma unroll
                    for (int r = 0; r < 4; ++r) {
                        const float pv = __expf(s[jt][r] - m_run);
                        s[jt][r] = pv;
                        rs += pv;
                    }
                }
                rs += __shfl_xor(rs, 16, 64);
                rs += __shfl_xor(rs, 32, 64);
                l_run += rs;
                const int q = qown + lo;
                #pragma unroll
                for (int jt = 0; jt < 4; ++jt) {
                    union { int i2[2]; uint64_t u; } pw;
                    pw.i2[0] = pkrtz(s[jt][0], s[jt][1]);
                    pw.i2[1] = pkrtz(s[jt][2], s[jt][3]);
                    *(uint64_t*)((char*)plds + q * 128 + ((jt * 32 + 8 * hi) ^ ((q & 7) << 4))) = pw.u;
                }
                if (hi == 0) sc_lds[q] = scv;
                if (lane == 0) flag_lds[w] = g ? 1 : 0;
            }
        }

        asm volatile("s_waitcnt lgkmcnt(0)" ::: "memory");
        if (kt + 1 < NT) {
            asm volatile("s_waitcnt vmcnt(1)" ::: "memory");
        } else {
            asm volatile("s_waitcnt vmcnt(0)" ::: "memory");
        }
        __builtin_amdgcn_sched_barrier(0);
        __builtin_amdgcn_s_barrier();      // B2
        asm volatile("" ::: "memory");

        // ---- PV phase
        if constexpr (!(MODE & 4)) {
            #pragma unroll
            for (int qt = 0; qt < 4; ++qt) {
                if (flag_lds[qt]) {
                    const float sc = sc_lds[qt * 16 + lo];
                    #pragma unroll
                    for (int ct = 0; ct < 2; ++ct) acc[ct][qt] *= sc;
                }
            }
            __builtin_amdgcn_s_setprio(1);
            #pragma unroll
            for (int ksp = 0; ksp < 2; ++ksp) {
                half8 pf[4];
                #pragma unroll
                for (int qt = 0; qt < 4; ++qt)
                    pf[qt] = *(const half8*)((const char*)plds + (qt * 16 + lo) * 128
                                             + ((ksp * 64 + 16 * hi) ^ ((lo & 7) << 4)));
                #pragma unroll
                for (int ct = 0; ct < 2; ++ct) {
                    const int vrow = cbase + ct * 16 + lo;
                    const half8 vf = *(const half8*)((const char*)kv + vrow * 128
                                                     + ((ksp * 64 + 16 * hi) ^ ((vrow & 7) << 4)));
                    #pragma unroll
                    for (int qt = 0; qt < 4; ++qt)
                        acc[ct][qt] = __builtin_amdgcn_mfma_f32_16x16x32_f16(vf, pf[qt], acc[ct][qt], 0, 0, 0);
                }
            }
            __builtin_amdgcn_s_setprio(0);
        }

        asm volatile("s_waitcnt lgkmcnt(0) vmcnt(0)" ::: "memory");
        __builtin_amdgcn_sched_barrier(0);
        __builtin_amdgcn_s_barrier();      // B3
        asm volatile("" ::: "memory");
        if constexpr (!(MODE & 1)) {
            if (kt + 1 < NT) STAGE_V(kt + 1)
            if (kt + 2 < NT) STAGE_K(kt + 2)
        }
    }
    #undef STAGE_K
    #undef STAGE_V

    if (w < 4 && hi == 0) {
        l_lds[qown + lo] = l_run;
        float2 v; v.x = m_run; v.y = l_run;
        pml[((size_t)split * BATCH + b) * NPOS + q0 + qown + lo] = v;
    }
    __syncthreads();
    float inv[4];
    #pragma unroll
    for (int qt = 0; qt < 4; ++qt) inv[qt] = 1.f / l_lds[qt * 16 + lo];
    f16* pob = po + (((size_t)split * BATCH + b) * CCH + cbase) * NPOS + q0;
    #pragma unroll
    for (int ct = 0; ct < 2; ++ct) {
        #pragma unroll
        for (int r = 0; r < 4; ++r) {
            const size_t rowo = (size_t)(ct * 16 + 4 * hi + r) * NPOS;
            #pragma unroll
            for (int qt = 0; qt < 4; ++qt)
                pob[rowo + qt * 16 + lo] = (f16)(acc[ct][qt][r] * inv[qt]);
        }
    }
}

// ---------------------------------------------------------------------------
// Merge NSPLIT partials, vectorized.
// ---------------------------------------------------------------------------
__global__ __launch_bounds__(256) void attn_merge(
    const f16* __restrict__ po,
    const float2* __restrict__ pml,
    const void* __restrict__ xraw,
    const uint32_t* __restrict__ mask_raw,
    const float* __restrict__ gamp,
    float* __restrict__ out_f,
    f16* __restrict__ out_h,
    int add_residual)
{
    const int b  = blockIdx.z;
    const int n0 = blockIdx.x * 64;
    const int c0 = blockIdx.y * 32;
    const int tid = threadIdx.x;
    const int cl  = tid >> 3;
    const int oct = tid & 7;

    __shared__ float wls[NSPLIT][64];
    if (tid < 64) {
        const int n = n0 + tid;
        float m[NSPLIT], l[NSPLIT];
        #pragma unroll
        for (int s = 0; s < NSPLIT; ++s) {
            float2 v = pml[((size_t)s * BATCH + b) * NPOS + n];
            m[s] = v.x; l[s] = v.y;
        }
        float M = m[0];
        #pragma unroll
        for (int s = 1; s < NSPLIT; ++s) M = fmaxf(M, m[s]);
        float wgt[NSPLIT], wsum = 0.f;
        #pragma unroll
        for (int s = 0; s < NSPLIT; ++s) { wgt[s] = __expf(m[s] - M) * l[s]; wsum += wgt[s]; }
        const float winv = 1.f / wsum;
        #pragma unroll
        for (int s = 0; s < NSPLIT; ++s) wls[s][tid] = wgt[s] * winv;
    }
    __syncthreads();

    const int c = c0 + cl;
    const int nl = oct * 8;
    const size_t base = ((size_t)b * CCH + c) * NPOS + n0 + nl;
    float o[8] = {0.f, 0.f, 0.f, 0.f, 0.f, 0.f, 0.f, 0.f};
    #pragma unroll
    for (int s = 0; s < NSPLIT; ++s) {
        const half8 pv = *(const half8*)(po + (((size_t)s * BATCH + b) * CCH + c) * NPOS + n0 + nl);
        const float* wr = &wls[s][nl];
        #pragma unroll
        for (int j = 0; j < 8; ++j) o[j] += wr[j] * (float)pv[j];
    }
    if (add_residual) {
        const bool bf = detect_bf16(mask_raw);
        const float gamma = gamp[0];
        float xv[8];
        load8(xraw, base, bf, xv);
        float4 f0, f1;
        f0.x = gamma * o[0] + xv[0]; f0.y = gamma * o[1] + xv[1];
        f0.z = gamma * o[2] + xv[2]; f0.w = gamma * o[3] + xv[3];
        f1.x = gamma * o[4] + xv[4]; f1.y = gamma * o[5] + xv[5];
        f1.z = gamma * o[6] + xv[6]; f1.w = gamma * o[7] + xv[7];
        *(float4*)(out_f + base) = f0;
        *(float4*)(out_f + base + 4) = f1;
    } else {
        half8 h;
        #pragma unroll
        for (int j = 0; j < 8; ++j) h[j] = (f16)o[j];
        *(half8*)(out_h + base) = h;
    }
}

// ---------------------------------------------------------------------------
// Per-(b,c) row variance epilogue. grid (C,B).
// ---------------------------------------------------------------------------
__global__ __launch_bounds__(256) void fmm_final(
    const float* __restrict__ x1f,
    const f16*  __restrict__ bg,
    const float* __restrict__ maskf,
    const float* __restrict__ gamp,
    const uint32_t* __restrict__ mask_raw,
    void* __restrict__ outp)
{
    const bool bf = detect_bf16(mask_raw);
    const int b = blockIdx.y;
    const int c = blockIdx.x;
    const int tid = threadIdx.x;
    const size_t rowoff = ((size_t)b * CCH + c) * NPOS;
    const float* xrow = x1f + rowoff;
    const f16*  grow = bg + rowoff;
    const float* mrow = maskf + (size_t)b * NPOS;

    float s_f = 0.f, ss_f = 0.f, s_g = 0.f, ss_g = 0.f;
    #pragma unroll
    for (int u = 0; u < 2; ++u) {
        const int i = tid * 16 + u * 8;
        const float4 x0 = *(const float4*)(xrow + i);
        const float4 x1v = *(const float4*)(xrow + i + 4);
        const float4 m0 = *(const float4*)(mrow + i);
        const float4 m1 = *(const float4*)(mrow + i + 4);
        half8 gv = *(const half8*)(grow + i);
        const float xs[8] = {x0.x, x0.y, x0.z, x0.w, x1v.x, x1v.y, x1v.z, x1v.w};
        const float ms[8] = {m0.x, m0.y, m0.z, m0.w, m1.x, m1.y, m1.z, m1.w};
        #pragma unroll
        for (int j = 0; j < 8; ++j) {
            const float f = xs[j] * ms[j];
            const float g = (float)gv[j];
            s_f += f; ss_f += f * f;
            s_g += g; ss_g += g * g;
        }
    }
    #pragma unroll
    for (int off = 1; off < 64; off <<= 1) {
        s_f += __shfl_xor(s_f, off, 64);
        ss_f += __shfl_xor(ss_f, off, 64);
        s_g += __shfl_xor(s_g, off, 64);
        ss_g += __shfl_xor(ss_g, off, 64);
    }
    __shared__ float red[4][4];
    const int wv_ = tid >> 6;
    if ((tid & 63) == 0) {
        red[wv_][0] = s_f; red[wv_][1] = ss_f; red[wv_][2] = s_g; red[wv_][3] = ss_g;
    }
    __syncthreads();
    s_f  = red[0][0] + red[1][0] + red[2][0] + red[3][0];
    ss_f = red[0][1] + red[1][1] + red[2][1] + red[3][1];
    s_g  = red[0][2] + red[1][2] + red[2][2] + red[3][2];
    ss_g = red[0][3] + red[1][3] + red[2][3] + red[3][3];

    const float nn = 4096.f, nm1 = 4095.f;
    const float var_f = (ss_f - s_f * s_f / nn) / nm1;
    const float var_g = (ss_g - s_g * s_g / nn) / nm1;
    const float ratio = sqrtf((var_g + 1e-5f) / (var_f + 1e-5f));
    const float gamma = gamp[0];

    #pragma unroll
    for (int u = 0; u < 2; ++u) {
        const int i = tid * 16 + u * 8;
        const float4 x0 = *(const float4*)(xrow + i);
        const float4 x1v = *(const float4*)(xrow + i + 4);
        const float4 m0 = *(const float4*)(mrow + i);
        const float4 m1 = *(const float4*)(mrow + i + 4);
        const float xs[8] = {x0.x, x0.y, x0.z, x0.w, x1v.x, x1v.y, x1v.z, x1v.w};
        const float ms[8] = {m0.x, m0.y, m0.z, m0.w, m1.x, m1.y, m1.z, m1.w};
        float ov[8];
        #pragma unroll
        for (int j = 0; j < 8; ++j)
            ov[j] = xs[j] + gamma * (xs[j] * ms[j]) * ratio;
        if (bf) {
            short8 sv;
            #pragma unroll
            for (int j = 0; j < 8; ++j) sv[j] = f2bf(ov[j]);
            *(short8*)((short*)outp + rowoff + i) = sv;
        } else {
            float4 f0 = {ov[0], ov[1], ov[2], ov[3]}, f1 = {ov[4], ov[5], ov[6], ov[7]};
            *(float4*)((float*)outp + rowoff + i) = f0;
            *(float4*)((float*)outp + rowoff + i + 4) = f1;
        }
    }
}

// ---------------------------------------------------------------------------
// DIAGNOSTIC ROUND: real pipeline is v7 (attn_split_t<0>, normal grid).
// Four ablation dispatches (4x grid, scratch po/pml, later fully overwritten
// by the real attn pass -> output unchanged) give per-phase timing via
// rocprof per-dispatch rows: M0 control, M1 no-stage, M2 no-owner, M3 no-PV.
// ---------------------------------------------------------------------------
extern "C" void kernel_launch(void* const* d_in, const int* in_sizes, int n_in,
                              void* d_out, int out_size, void* d_ws, size_t ws_size,
                              hipStream_t stream)
{
    const size_t MB = 1u << 20, KB = 1u << 10;
    char* ws = (char*)d_ws;
    f16*    qkbuf = (f16*)(ws);
    f16*    vbuf  = (f16*)(ws + 1 * MB);
    f16*    bgbuf = (f16*)(ws);
    float*  x1f   = (float*)(ws + 5 * MB);
    f16*    po    = (f16*)(ws + 13 * MB);
    float2* pml   = (float2*)(ws + 29 * MB);
    float*  maskf = (float*)(ws + 29 * MB + 512 * KB);
    f16*    w1qk  = (f16*)(ws + 30 * MB);
    f16*    w1v   = (f16*)(ws + 30 * MB + 32 * KB);
    f16*    b1    = (f16*)(ws + 30 * MB + 160 * KB);
    f16*    w2qk  = (f16*)(ws + 30 * MB + 164 * KB);
    f16*    w2v   = (f16*)(ws + 30 * MB + 196 * KB);
    f16*    b2    = (f16*)(ws + 30 * MB + 324 * KB);
    float*  gam   = (float*)(ws + 30 * MB + 328 * KB);

    const uint32_t* mraw = (const uint32_t*)d_in[1];

    dim3 blk(256);
    dim3 ablk(512);
    dim3 vgrid(85);
    dim3 cgrid(NPOS / 32, BATCH);
    dim3 agrid(NPOS / 64, NSPLIT, BATCH);
    dim3 dgrid(NPOS / 64 * 4, NSPLIT, BATCH);   // 4x for diagnostics
    dim3 mgrid(NPOS / 64, CCH / 32, BATCH);
    dim3 fgrid(CCH, BATCH);

    convert_inputs<<<vgrid, blk, 0, stream>>>(
        mraw,
        d_in[2], d_in[4], d_in[6], d_in[3], d_in[5], d_in[7], d_in[8],
        d_in[9], d_in[11], d_in[13], d_in[10], d_in[12], d_in[14], d_in[15],
        maskf, w1qk, w1v, b1, w2qk, w2v, b2, gam);

    // pass 1 conv
    conv_qkv<<<cgrid, blk, 0, stream>>>(d_in[0], 1, mraw, w1qk, w1v, b1, maskf, 0, qkbuf, vbuf);

    // ---- ablation diagnostics (scratch writes; overwritten by real attn) ----
    attn_split_t<0><<<dgrid, ablk, 0, stream>>>(qkbuf, vbuf, po, pml);  // control
    attn_split_t<1><<<dgrid, ablk, 0, stream>>>(qkbuf, vbuf, po, pml);  // no staging
    attn_split_t<2><<<dgrid, ablk, 0, stream>>>(qkbuf, vbuf, po, pml);  // no owner
    attn_split_t<4><<<dgrid, ablk, 0, stream>>>(qkbuf, vbuf, po, pml);  // no PV

    // pass 1: x1 = sa_gamma * attn(x) + x
    attn_split_t<0><<<agrid, ablk, 0, stream>>>(qkbuf, vbuf, po, pml);
    attn_merge<<<mgrid, blk, 0, stream>>>(po, pml, d_in[0], mraw, gam + 0, x1f, nullptr, 1);
    // pass 2: bg = attn(mask*x1 -> q; (1-mask)*x1 -> k,v)
    conv_qkv<<<cgrid, blk, 0, stream>>>(x1f, 0, mraw, w2qk, w2v, b2, maskf, 1, qkbuf, vbuf);
    attn_split_t<0><<<agrid, ablk, 0, stream>>>(qkbuf, vbuf, po, pml);
    attn_merge<<<mgrid, blk, 0, stream>>>(po, pml, nullptr, mraw, gam + 1, nullptr, bgbuf, 0);
    // FMM epilogue
    fmm_final<<<fgrid, blk, 0, stream>>>(x1f, bgbuf, maskf, gam + 1, mraw, d_out);
}

// Round 13
// 121.392 us; speedup vs baseline: 4.1574x; 4.1574x over previous
//
#include <hip/hip_runtime.h>
#include <stdint.h>

typedef _Float16 f16;
typedef __attribute__((ext_vector_type(8))) _Float16 half8;
typedef __attribute__((ext_vector_type(2))) __fp16 fp16x2;
typedef __attribute__((ext_vector_type(8))) short short8;
typedef __attribute__((ext_vector_type(4))) float f32x4;

#define NPOS 4096
#define CCH  256
#define OQK  64
#define BATCH 2
#define NSPLIT 4
#define KEYS_PER_SPLIT 1024
#define NT (KEYS_PER_SPLIT / 64)

typedef __attribute__((address_space(3))) uint32_t lds_u32;
typedef __attribute__((address_space(1))) const uint32_t glb_u32;

__device__ __forceinline__ float bf2f(short u) {
    union { uint32_t i; float f; } c;
    c.i = ((uint32_t)(uint16_t)u) << 16;
    return c.f;
}
__device__ __forceinline__ short f2bf(float f) {
    union { float f; uint32_t i; } c; c.f = f;
    uint32_t lsb = (c.i >> 16) & 1u;
    c.i += 0x7FFFu + lsb;
    return (short)(c.i >> 16);
}

// Deterministic dtype sniff: mask values are exactly {0.0,1.0}.
__device__ __forceinline__ bool detect_bf16(const uint32_t* mw) {
    int hits = 0;
    #pragma unroll
    for (int i = 0; i < 64; ++i) hits += ((mw[i] & 0xFFFFu) == 0x3F80u) ? 1 : 0;
    return hits != 0;
}

__device__ __forceinline__ void load8(const void* base, size_t e0, bool bf, float* v) {
    if (bf) {
        short8 s = *(const short8*)((const short*)base + e0);
        #pragma unroll
        for (int j = 0; j < 8; ++j) v[j] = bf2f(s[j]);
    } else {
        const float* fp = (const float*)base + e0;
        float4 a = *(const float4*)fp;
        float4 b = *(const float4*)(fp + 4);
        v[0] = a.x; v[1] = a.y; v[2] = a.z; v[3] = a.w;
        v[4] = b.x; v[5] = b.y; v[6] = b.z; v[7] = b.w;
    }
}
__device__ __forceinline__ float load1(const void* base, int i, bool bf) {
    return bf ? bf2f(((const short*)base)[i]) : ((const float*)base)[i];
}

__device__ __forceinline__ int pkrtz(float a, float b) {
    union { fp16x2 h; int i; } u;
    u.h = __builtin_amdgcn_cvt_pkrtz(a, b);
    return u.i;
}

// ---------------------------------------------------------------------------
// Canonicalize small inputs. grid = 85 blocks x 256.
// ---------------------------------------------------------------------------
__global__ __launch_bounds__(256) void convert_inputs(
    const uint32_t* __restrict__ mask_raw,
    const void* __restrict__ w1q, const void* __restrict__ w1k, const void* __restrict__ w1v_,
    const void* __restrict__ b1q, const void* __restrict__ b1k, const void* __restrict__ b1v_,
    const void* __restrict__ g1,
    const void* __restrict__ w2q, const void* __restrict__ w2k, const void* __restrict__ w2v_,
    const void* __restrict__ b2q, const void* __restrict__ b2k, const void* __restrict__ b2v_,
    const void* __restrict__ g2,
    float* __restrict__ maskf,
    f16* __restrict__ w1qk, f16* __restrict__ w1vm, f16* __restrict__ b1,
    f16* __restrict__ w2qk, f16* __restrict__ w2vm, f16* __restrict__ b2,
    float* __restrict__ gam)
{
    const bool bf = detect_bf16(mask_raw);
    const int blk = blockIdx.x, tid = threadIdx.x;
    float v[8];
    if (blk < 4) {                          // mask: 8192
        const size_t e0 = ((size_t)blk * 256 + tid) * 8;
        load8(mask_raw, e0, bf, v);
        float4 f0 = {v[0], v[1], v[2], v[3]}, f1 = {v[4], v[5], v[6], v[7]};
        *(float4*)(maskf + e0) = f0;
        *(float4*)(maskf + e0 + 4) = f1;
    } else if (blk < 12) {                  // w1qk: 16384
        const size_t g = ((size_t)(blk - 4) * 256 + tid) * 8;
        const int o = (int)(g >> 8), cc = (int)(g & 255);
        const void* src = (o < 32) ? w1q : w1k;
        const size_t se = (size_t)((o < 32) ? o : o - 32) * 256 + cc;
        load8(src, se, bf, v);
        half8 h;
        #pragma unroll
        for (int j = 0; j < 8; ++j) h[j] = (f16)v[j];
        *(half8*)(w1qk + g) = h;
    } else if (blk < 44) {                  // w1v: 65536
        const size_t g = ((size_t)(blk - 12) * 256 + tid) * 8;
        load8(w1v_, g, bf, v);
        half8 h;
        #pragma unroll
        for (int j = 0; j < 8; ++j) h[j] = (f16)v[j];
        *(half8*)(w1vm + g) = h;
    } else if (blk < 52) {                  // w2qk
        const size_t g = ((size_t)(blk - 44) * 256 + tid) * 8;
        const int o = (int)(g >> 8), cc = (int)(g & 255);
        const void* src = (o < 32) ? w2q : w2k;
        const size_t se = (size_t)((o < 32) ? o : o - 32) * 256 + cc;
        load8(src, se, bf, v);
        half8 h;
        #pragma unroll
        for (int j = 0; j < 8; ++j) h[j] = (f16)v[j];
        *(half8*)(w2qk + g) = h;
    } else if (blk < 84) {                  // w2v
        const size_t g = ((size_t)(blk - 52) * 256 + tid) * 8;
        load8(w2v_, g, bf, v);
        half8 h;
        #pragma unroll
        for (int j = 0; j < 8; ++j) h[j] = (f16)v[j];
        *(half8*)(w2vm + g) = h;
    } else {                                // biases + gammas
        for (int i = tid; i < 320; i += 256) {
            const void* s1 = (i < 32) ? b1q : (i < 64) ? b1k : b1v_;
            const void* s2 = (i < 32) ? b2q : (i < 64) ? b2k : b2v_;
            const int ii = (i < 32) ? i : (i < 64) ? i - 32 : i - 64;
            b1[i] = (f16)load1(s1, ii, bf);
            b2[i] = (f16)load1(s2, ii, bf);
        }
        if (tid == 0) {
            gam[0] = load1(g1, 0, bf);
            gam[1] = load1(g2, 0, bf);
        }
    }
}

// ---------------------------------------------------------------------------
// Fused 1x1 conv: q,k packed (B,N,64); v (B,C,N); f16 out.
// ---------------------------------------------------------------------------
__global__ __launch_bounds__(256) void conv_qkv(
    const void* __restrict__ xin, int is_raw,
    const uint32_t* __restrict__ mask_raw,
    const f16* __restrict__ wqk,
    const f16* __restrict__ wvm,
    const f16* __restrict__ bias,
    const float* __restrict__ maskf, int use_mask,
    f16* __restrict__ qkout,
    f16* __restrict__ vout)
{
    const bool bf = is_raw ? detect_bf16(mask_raw) : false;
    const int b    = blockIdx.y;
    const int n0   = blockIdx.x * 32;
    const int tid  = threadIdx.x;
    const int lane = tid & 63;
    const int w    = tid >> 6;
    const int lo   = lane & 15;
    const int hi   = lane >> 4;

    __shared__ f16 xt[32 * 256];   // [n][c], 16 KB

    {
        const int nc = tid & 3;
        const int cg = tid >> 2;
        #pragma unroll
        for (int it = 0; it < 4; ++it) {
            const int c = cg + 64 * it;
            const size_t off = ((size_t)b * CCH + c) * NPOS + n0 + nc * 8;
            float v8[8];
            load8(xin, off, bf, v8);
            #pragma unroll
            for (int j = 0; j < 8; ++j) {
                const int n = nc * 8 + j;
                int byte = n * 512 + c * 2;
                byte ^= ((n & 7) << 4);
                *(f16*)((char*)xt + byte) = (f16)v8[j];
            }
        }
    }
    __syncthreads();

    const f32x4 z = {0.f, 0.f, 0.f, 0.f};
    f32x4 acc_qk[2];
    f32x4 acc_v[4][2];
    #pragma unroll
    for (int i = 0; i < 2; ++i) {
        acc_qk[i] = z;
        #pragma unroll
        for (int j = 0; j < 4; ++j) acc_v[j][i] = z;
    }

    #pragma unroll 1
    for (int ks = 0; ks < 8; ++ks) {
        const int ce = ks * 32 + 8 * hi;
        half8 xfr[2];
        #pragma unroll
        for (int nt = 0; nt < 2; ++nt) {
            const int n = nt * 16 + lo;
            int byte = n * 512 + ce * 2;
            byte ^= ((n & 7) << 4);
            xfr[nt] = *(const half8*)((const char*)xt + byte);
        }
        {
            half8 wf = *(const half8*)(wqk + (size_t)(w * 16 + lo) * 256 + ce);
            #pragma unroll
            for (int nt = 0; nt < 2; ++nt)
                acc_qk[nt] = __builtin_amdgcn_mfma_f32_16x16x32_f16(xfr[nt], wf, acc_qk[nt], 0, 0, 0);
        }
        #pragma unroll
        for (int ot = 0; ot < 4; ++ot) {
            half8 wf = *(const half8*)(wvm + (size_t)(w * 64 + ot * 16 + lo) * 256 + ce);
            #pragma unroll
            for (int nt = 0; nt < 2; ++nt)
                acc_v[ot][nt] = __builtin_amdgcn_mfma_f32_16x16x32_f16(wf, xfr[nt], acc_v[ot][nt], 0, 0, 0);
        }
    }

    {
        const int o = w * 16 + lo;
        const float bb = (float)bias[o];
        #pragma unroll
        for (int nt = 0; nt < 2; ++nt) {
            #pragma unroll
            for (int r = 0; r < 4; ++r) {
                const int n = n0 + nt * 16 + 4 * hi + r;
                float mult = 1.f;
                if (use_mask) {
                    const float mv = maskf[b * NPOS + n];
                    mult = (o < 32) ? mv : (1.f - mv);
                }
                qkout[((size_t)b * NPOS + n) * OQK + o] = (f16)(mult * acc_qk[nt][r] + bb);
            }
        }
    }
    {
        float mv_n[2];
        #pragma unroll
        for (int nt = 0; nt < 2; ++nt)
            mv_n[nt] = use_mask ? (1.f - maskf[b * NPOS + n0 + nt * 16 + lo]) : 1.f;
        #pragma unroll
        for (int ot = 0; ot < 4; ++ot) {
            #pragma unroll
            for (int r = 0; r < 4; ++r) {
                const int oc = w * 64 + ot * 16 + 4 * hi + r;
                const float bb = (float)bias[64 + oc];
                #pragma unroll
                for (int nt = 0; nt < 2; ++nt) {
                    const int n = n0 + nt * 16 + lo;
                    vout[((size_t)b * CCH + oc) * NPOS + n] = (f16)(mv_n[nt] * acc_v[ot][nt][r] + bb);
                }
            }
        }
    }
}

// ---------------------------------------------------------------------------
// Split-KV flash attention v8 = v7 + XCD-pinned flat grid.
// grid = 512 x 1; block id = qblk*8 + (b*4+split), so all 64 q-blocks of a
// (split,b) pair share one XCD (dispatch round-robins id%8 -> XCD) and its
// 1MB K/V-split working set stays in that XCD's private 4MB L2.
// Body: 512 thr / 8 waves; waves 0-3 own softmax of q-slab, all 8 do PV on a
// c-eighth; counted-vmcnt pipeline, raw barriers; K double-buffered.
// ---------------------------------------------------------------------------
__global__ __launch_bounds__(512, 4) void attn_split(
    const f16* __restrict__ qk,      // (B,N,64): q at d 0-31, k at d 32-63
    const f16* __restrict__ vbuf,    // (B,C,N)
    f16* __restrict__ po,            // (NSPLIT,B,C,N)
    float2* __restrict__ pml)        // (NSPLIT,B,N)
{
    const int id    = blockIdx.x;
    const int xg    = id & 7;              // = b*4 + split (XCD-pinned)
    const int split = xg & 3;
    const int b     = xg >> 2;
    const int q0    = (id >> 3) * 64;      // q-block
    const int tid   = threadIdx.x;
    const int lane  = tid & 63;
    const int w     = tid >> 6;
    const int lo    = lane & 15;
    const int hi    = lane >> 4;
    const int qown  = (w & 3) * 16;
    const int cbase = w * 32;

    __shared__ f16 kv[CCH * 64];
    __shared__ f16 kbuf[2][64 * 64];
    __shared__ f16 plds[64 * 64];
    __shared__ float sc_lds[64];
    __shared__ float l_lds[64];
    __shared__ int   flag_lds[4];

    const int trow = tid >> 3;
    const int tch  = tid & 7;

    half8 qfrag;
    if (w < 4)
        qfrag = *(const half8*)(qk + ((size_t)b * NPOS + q0 + qown + lo) * OQK + 8 * hi);

    const f32x4 z = {0.f, 0.f, 0.f, 0.f};
    f32x4 acc[2][4];
    #pragma unroll
    for (int i = 0; i < 2; ++i)
        #pragma unroll
        for (int j = 0; j < 4; ++j) acc[i][j] = z;
    float m_run = -3.0e38f, l_run = 0.f;

    const f16* vsrc = vbuf + (size_t)b * CCH * NPOS;
    const f16* ksrc = qk + (size_t)b * NPOS * OQK;

    #define STAGE_V(kt)                                                        \
    {                                                                          \
        const int j0s = split * KEYS_PER_SPLIT + (kt) * 64;                    \
        _Pragma("unroll")                                                      \
        for (int i = 0; i < 4; ++i) {                                          \
            const int c = i * 64 + trow;                                       \
            const f16* g = vsrc + (size_t)c * NPOS + j0s + ((tch ^ (c & 7)) * 8); \
            char* d = (char*)kv + i * 8192 + w * 1024;                         \
            __builtin_amdgcn_global_load_lds((glb_u32*)g, (lds_u32*)d, 16, 0, 0); \
        }                                                                      \
    }
    #define STAGE_K(kt)                                                        \
    {                                                                          \
        const int j0s = split * KEYS_PER_SPLIT + (kt) * 64;                    \
        char* kb = (char*)kbuf + ((kt) & 1) * 8192;                            \
        const f16* g = ksrc + (size_t)(j0s + trow) * OQK + ((tch ^ (trow & 7)) * 8); \
        __builtin_amdgcn_global_load_lds((glb_u32*)g, (lds_u32*)(kb + w * 1024), 16, 0, 0); \
    }

    STAGE_V(0)
    STAGE_K(0)
    STAGE_K(1)
    asm volatile("s_waitcnt vmcnt(1)" ::: "memory");
    __builtin_amdgcn_s_barrier();
    asm volatile("" ::: "memory");

    #pragma unroll 1
    for (int kt = 0; kt < NT; ++kt) {
        // ---- owner phase (waves 0-3); V(kt)/K(kt+1) may be in flight
        if (w < 4) {
            const char* kb = (const char*)kbuf + (kt & 1) * 8192;
            f32x4 s[4];
            __builtin_amdgcn_s_setprio(1);
            #pragma unroll
            for (int jt = 0; jt < 4; ++jt) {
                const int krow = jt * 16 + lo;
                const half8 kfrag = *(const half8*)(kb + krow * 128
                                                    + ((64 + hi * 16) ^ ((krow & 7) << 4)));
                s[jt] = __builtin_amdgcn_mfma_f32_16x16x32_f16(kfrag, qfrag, z, 0, 0, 0);
            }
            __builtin_amdgcn_s_setprio(0);
            float pm = s[0][0];
            #pragma unroll
            for (int jt = 0; jt < 4; ++jt)
                #pragma unroll
                for (int r = 0; r < 4; ++r) pm = fmaxf(pm, s[jt][r]);
            pm = fmaxf(pm, __shfl_xor(pm, 16, 64));
            pm = fmaxf(pm, __shfl_xor(pm, 32, 64));
            const bool g = __any(pm - m_run > 8.f);    // defer-max THR=8
            float scv = 1.f;
            if (g) {
                const float mnew = fmaxf(m_run, pm);
                scv = __expf(m_run - mnew);
                m_run = mnew;
                l_run *= scv;
            }
            float rs = 0.f;
            #pragma unroll
            for (int jt = 0; jt < 4; ++jt) {
                #pragma unroll
                for (int r = 0; r < 4; ++r) {
                    const float pv = __expf(s[jt][r] - m_run);
                    s[jt][r] = pv;
                    rs += pv;
                }
            }
            rs += __shfl_xor(rs, 16, 64);
            rs += __shfl_xor(rs, 32, 64);
            l_run += rs;
            const int q = qown + lo;
            #pragma unroll
            for (int jt = 0; jt < 4; ++jt) {
                union { int i2[2]; uint64_t u; } pw;
                pw.i2[0] = pkrtz(s[jt][0], s[jt][1]);
                pw.i2[1] = pkrtz(s[jt][2], s[jt][3]);
                *(uint64_t*)((char*)plds + q * 128 + ((jt * 32 + 8 * hi) ^ ((q & 7) << 4))) = pw.u;
            }
            if (hi == 0) sc_lds[q] = scv;
            if (lane == 0) flag_lds[w] = g ? 1 : 0;
        }

        asm volatile("s_waitcnt lgkmcnt(0)" ::: "memory");
        if (kt + 1 < NT) {
            asm volatile("s_waitcnt vmcnt(1)" ::: "memory");
        } else {
            asm volatile("s_waitcnt vmcnt(0)" ::: "memory");
        }
        __builtin_amdgcn_sched_barrier(0);
        __builtin_amdgcn_s_barrier();      // B2
        asm volatile("" ::: "memory");

        // ---- PV phase: c-eighth [32w,+32) x q 0..63
        #pragma unroll
        for (int qt = 0; qt < 4; ++qt) {
            if (flag_lds[qt]) {
                const float sc = sc_lds[qt * 16 + lo];
                #pragma unroll
                for (int ct = 0; ct < 2; ++ct) acc[ct][qt] *= sc;
            }
        }
        __builtin_amdgcn_s_setprio(1);
        #pragma unroll
        for (int ksp = 0; ksp < 2; ++ksp) {
            half8 pf[4];
            #pragma unroll
            for (int qt = 0; qt < 4; ++qt)
                pf[qt] = *(const half8*)((const char*)plds + (qt * 16 + lo) * 128
                                         + ((ksp * 64 + 16 * hi) ^ ((lo & 7) << 4)));
            #pragma unroll
            for (int ct = 0; ct < 2; ++ct) {
                const int vrow = cbase + ct * 16 + lo;
                const half8 vf = *(const half8*)((const char*)kv + vrow * 128
                                                 + ((ksp * 64 + 16 * hi) ^ ((vrow & 7) << 4)));
                #pragma unroll
                for (int qt = 0; qt < 4; ++qt)
                    acc[ct][qt] = __builtin_amdgcn_mfma_f32_16x16x32_f16(vf, pf[qt], acc[ct][qt], 0, 0, 0);
            }
        }
        __builtin_amdgcn_s_setprio(0);

        asm volatile("s_waitcnt lgkmcnt(0) vmcnt(0)" ::: "memory");
        __builtin_amdgcn_sched_barrier(0);
        __builtin_amdgcn_s_barrier();      // B3
        asm volatile("" ::: "memory");
        if (kt + 1 < NT) STAGE_V(kt + 1)
        if (kt + 2 < NT) STAGE_K(kt + 2)
    }
    #undef STAGE_K
    #undef STAGE_V

    if (w < 4 && hi == 0) {
        l_lds[qown + lo] = l_run;
        float2 v; v.x = m_run; v.y = l_run;
        pml[((size_t)split * BATCH + b) * NPOS + q0 + qown + lo] = v;
    }
    __syncthreads();
    float inv[4];
    #pragma unroll
    for (int qt = 0; qt < 4; ++qt) inv[qt] = 1.f / l_lds[qt * 16 + lo];
    f16* pob = po + (((size_t)split * BATCH + b) * CCH + cbase) * NPOS + q0;
    #pragma unroll
    for (int ct = 0; ct < 2; ++ct) {
        #pragma unroll
        for (int r = 0; r < 4; ++r) {
            const size_t rowo = (size_t)(ct * 16 + 4 * hi + r) * NPOS;
            #pragma unroll
            for (int qt = 0; qt < 4; ++qt)
                pob[rowo + qt * 16 + lo] = (f16)(acc[ct][qt][r] * inv[qt]);
        }
    }
}

// ---------------------------------------------------------------------------
// Merge NSPLIT partials, vectorized.
// ---------------------------------------------------------------------------
__global__ __launch_bounds__(256) void attn_merge(
    const f16* __restrict__ po,
    const float2* __restrict__ pml,
    const void* __restrict__ xraw,
    const uint32_t* __restrict__ mask_raw,
    const float* __restrict__ gamp,
    float* __restrict__ out_f,
    f16* __restrict__ out_h,
    int add_residual)
{
    const int b  = blockIdx.z;
    const int n0 = blockIdx.x * 64;
    const int c0 = blockIdx.y * 32;
    const int tid = threadIdx.x;
    const int cl  = tid >> 3;
    const int oct = tid & 7;

    __shared__ float wls[NSPLIT][64];
    if (tid < 64) {
        const int n = n0 + tid;
        float m[NSPLIT], l[NSPLIT];
        #pragma unroll
        for (int s = 0; s < NSPLIT; ++s) {
            float2 v = pml[((size_t)s * BATCH + b) * NPOS + n];
            m[s] = v.x; l[s] = v.y;
        }
        float M = m[0];
        #pragma unroll
        for (int s = 1; s < NSPLIT; ++s) M = fmaxf(M, m[s]);
        float wgt[NSPLIT], wsum = 0.f;
        #pragma unroll
        for (int s = 0; s < NSPLIT; ++s) { wgt[s] = __expf(m[s] - M) * l[s]; wsum += wgt[s]; }
        const float winv = 1.f / wsum;
        #pragma unroll
        for (int s = 0; s < NSPLIT; ++s) wls[s][tid] = wgt[s] * winv;
    }
    __syncthreads();

    const int c = c0 + cl;
    const int nl = oct * 8;
    const size_t base = ((size_t)b * CCH + c) * NPOS + n0 + nl;
    float o[8] = {0.f, 0.f, 0.f, 0.f, 0.f, 0.f, 0.f, 0.f};
    #pragma unroll
    for (int s = 0; s < NSPLIT; ++s) {
        const half8 pv = *(const half8*)(po + (((size_t)s * BATCH + b) * CCH + c) * NPOS + n0 + nl);
        const float* wr = &wls[s][nl];
        #pragma unroll
        for (int j = 0; j < 8; ++j) o[j] += wr[j] * (float)pv[j];
    }
    if (add_residual) {
        const bool bf = detect_bf16(mask_raw);
        const float gamma = gamp[0];
        float xv[8];
        load8(xraw, base, bf, xv);
        float4 f0, f1;
        f0.x = gamma * o[0] + xv[0]; f0.y = gamma * o[1] + xv[1];
        f0.z = gamma * o[2] + xv[2]; f0.w = gamma * o[3] + xv[3];
        f1.x = gamma * o[4] + xv[4]; f1.y = gamma * o[5] + xv[5];
        f1.z = gamma * o[6] + xv[6]; f1.w = gamma * o[7] + xv[7];
        *(float4*)(out_f + base) = f0;
        *(float4*)(out_f + base + 4) = f1;
    } else {
        half8 h;
        #pragma unroll
        for (int j = 0; j < 8; ++j) h[j] = (f16)o[j];
        *(half8*)(out_h + base) = h;
    }
}

// ---------------------------------------------------------------------------
// Per-(b,c) row variance epilogue. grid (C,B).
// ---------------------------------------------------------------------------
__global__ __launch_bounds__(256) void fmm_final(
    const float* __restrict__ x1f,
    const f16*  __restrict__ bg,
    const float* __restrict__ maskf,
    const float* __restrict__ gamp,
    const uint32_t* __restrict__ mask_raw,
    void* __restrict__ outp)
{
    const bool bf = detect_bf16(mask_raw);
    const int b = blockIdx.y;
    const int c = blockIdx.x;
    const int tid = threadIdx.x;
    const size_t rowoff = ((size_t)b * CCH + c) * NPOS;
    const float* xrow = x1f + rowoff;
    const f16*  grow = bg + rowoff;
    const float* mrow = maskf + (size_t)b * NPOS;

    float s_f = 0.f, ss_f = 0.f, s_g = 0.f, ss_g = 0.f;
    #pragma unroll
    for (int u = 0; u < 2; ++u) {
        const int i = tid * 16 + u * 8;
        const float4 x0 = *(const float4*)(xrow + i);
        const float4 x1v = *(const float4*)(xrow + i + 4);
        const float4 m0 = *(const float4*)(mrow + i);
        const float4 m1 = *(const float4*)(mrow + i + 4);
        half8 gv = *(const half8*)(grow + i);
        const float xs[8] = {x0.x, x0.y, x0.z, x0.w, x1v.x, x1v.y, x1v.z, x1v.w};
        const float ms[8] = {m0.x, m0.y, m0.z, m0.w, m1.x, m1.y, m1.z, m1.w};
        #pragma unroll
        for (int j = 0; j < 8; ++j) {
            const float f = xs[j] * ms[j];
            const float g = (float)gv[j];
            s_f += f; ss_f += f * f;
            s_g += g; ss_g += g * g;
        }
    }
    #pragma unroll
    for (int off = 1; off < 64; off <<= 1) {
        s_f += __shfl_xor(s_f, off, 64);
        ss_f += __shfl_xor(ss_f, off, 64);
        s_g += __shfl_xor(s_g, off, 64);
        ss_g += __shfl_xor(ss_g, off, 64);
    }
    __shared__ float red[4][4];
    const int wv_ = tid >> 6;
    if ((tid & 63) == 0) {
        red[wv_][0] = s_f; red[wv_][1] = ss_f; red[wv_][2] = s_g; red[wv_][3] = ss_g;
    }
    __syncthreads();
    s_f  = red[0][0] + red[1][0] + red[2][0] + red[3][0];
    ss_f = red[0][1] + red[1][1] + red[2][1] + red[3][1];
    s_g  = red[0][2] + red[1][2] + red[2][2] + red[3][2];
    ss_g = red[0][3] + red[1][3] + red[2][3] + red[3][3];

    const float nn = 4096.f, nm1 = 4095.f;
    const float var_f = (ss_f - s_f * s_f / nn) / nm1;
    const float var_g = (ss_g - s_g * s_g / nn) / nm1;
    const float ratio = sqrtf((var_g + 1e-5f) / (var_f + 1e-5f));
    const float gamma = gamp[0];

    #pragma unroll
    for (int u = 0; u < 2; ++u) {
        const int i = tid * 16 + u * 8;
        const float4 x0 = *(const float4*)(xrow + i);
        const float4 x1v = *(const float4*)(xrow + i + 4);
        const float4 m0 = *(const float4*)(mrow + i);
        const float4 m1 = *(const float4*)(mrow + i + 4);
        const float xs[8] = {x0.x, x0.y, x0.z, x0.w, x1v.x, x1v.y, x1v.z, x1v.w};
        const float ms[8] = {m0.x, m0.y, m0.z, m0.w, m1.x, m1.y, m1.z, m1.w};
        float ov[8];
        #pragma unroll
        for (int j = 0; j < 8; ++j)
            ov[j] = xs[j] + gamma * (xs[j] * ms[j]) * ratio;
        if (bf) {
            short8 sv;
            #pragma unroll
            for (int j = 0; j < 8; ++j) sv[j] = f2bf(ov[j]);
            *(short8*)((short*)outp + rowoff + i) = sv;
        } else {
            float4 f0 = {ov[0], ov[1], ov[2], ov[3]}, f1 = {ov[4], ov[5], ov[6], ov[7]};
            *(float4*)((float*)outp + rowoff + i) = f0;
            *(float4*)((float*)outp + rowoff + i + 4) = f1;
        }
    }
}

// ---------------------------------------------------------------------------
// ws map: qk[0,1M) v[1M,5M) | bg[0,4M) after attn2 | x1f[5M,13M)
//   po[13M,29M) pml[29M,+256K) maskf@29M+512K w*@30M  (~30.4 MB total)
// ---------------------------------------------------------------------------
extern "C" void kernel_launch(void* const* d_in, const int* in_sizes, int n_in,
                              void* d_out, int out_size, void* d_ws, size_t ws_size,
                              hipStream_t stream)
{
    const size_t MB = 1u << 20, KB = 1u << 10;
    char* ws = (char*)d_ws;
    f16*    qkbuf = (f16*)(ws);
    f16*    vbuf  = (f16*)(ws + 1 * MB);
    f16*    bgbuf = (f16*)(ws);
    float*  x1f   = (float*)(ws + 5 * MB);
    f16*    po    = (f16*)(ws + 13 * MB);
    float2* pml   = (float2*)(ws + 29 * MB);
    float*  maskf = (float*)(ws + 29 * MB + 512 * KB);
    f16*    w1qk  = (f16*)(ws + 30 * MB);
    f16*    w1v   = (f16*)(ws + 30 * MB + 32 * KB);
    f16*    b1    = (f16*)(ws + 30 * MB + 160 * KB);
    f16*    w2qk  = (f16*)(ws + 30 * MB + 164 * KB);
    f16*    w2v   = (f16*)(ws + 30 * MB + 196 * KB);
    f16*    b2    = (f16*)(ws + 30 * MB + 324 * KB);
    float*  gam   = (float*)(ws + 30 * MB + 328 * KB);

    const uint32_t* mraw = (const uint32_t*)d_in[1];

    dim3 blk(256);
    dim3 ablk(512);
    dim3 vgrid(85);
    dim3 cgrid(NPOS / 32, BATCH);
    dim3 agrid(NPOS / 64 * NSPLIT * BATCH);   // flat, XCD-pinned decode
    dim3 mgrid(NPOS / 64, CCH / 32, BATCH);
    dim3 fgrid(CCH, BATCH);

    convert_inputs<<<vgrid, blk, 0, stream>>>(
        mraw,
        d_in[2], d_in[4], d_in[6], d_in[3], d_in[5], d_in[7], d_in[8],
        d_in[9], d_in[11], d_in[13], d_in[10], d_in[12], d_in[14], d_in[15],
        maskf, w1qk, w1v, b1, w2qk, w2v, b2, gam);

    // pass 1: x1 = sa_gamma * attn(x) + x   (x1f f32)
    conv_qkv<<<cgrid, blk, 0, stream>>>(d_in[0], 1, mraw, w1qk, w1v, b1, maskf, 0, qkbuf, vbuf);
    attn_split<<<agrid, ablk, 0, stream>>>(qkbuf, vbuf, po, pml);
    attn_merge<<<mgrid, blk, 0, stream>>>(po, pml, d_in[0], mraw, gam + 0, x1f, nullptr, 1);
    // pass 2: bg = attn(mask*x1 -> q; (1-mask)*x1 -> k,v)
    conv_qkv<<<cgrid, blk, 0, stream>>>(x1f, 0, mraw, w2qk, w2v, b2, maskf, 1, qkbuf, vbuf);
    attn_split<<<agrid, ablk, 0, stream>>>(qkbuf, vbuf, po, pml);
    attn_merge<<<mgrid, blk, 0, stream>>>(po, pml, nullptr, mraw, gam + 1, nullptr, bgbuf, 0);
    // FMM epilogue
    fmm_final<<<fgrid, blk, 0, stream>>>(x1f, bgbuf, maskf, gam + 1, mraw, d_out);
}